// Round 21
// baseline (184.322 us; speedup 1.0000x reference)
//
#include <hip/hip_runtime.h>
#include <hip/hip_bf16.h>

// GATv2 2-layer GNN. Round 21: L1 GEMM A-path gets a 2-deep register pipeline
// (load A(t+2) early, pack+ds_write A(t+1) BEFORE the MFMA cluster) so the
// fp32 stream's HBM latency is covered by a full K-tile and the pack overlaps
// other waves' MFMA. Everything else = round 20.
// N=32768 (64 graphs x 512), F=512, E=262144 (+N self loops), H=4, C1=128, C2=64.

typedef __bf16 bf16_t;
typedef bf16_t bf16x8 __attribute__((ext_vector_type(8)));
typedef float f32x4 __attribute__((ext_vector_type(4)));
typedef unsigned short ushort8 __attribute__((ext_vector_type(8)));

__device__ __forceinline__ unsigned short f2bf_rn(float f) {
    unsigned u = __float_as_uint(f);
    unsigned r = (u + 0x7FFFu + ((u >> 16) & 1u)) >> 16;
    return (unsigned short)r;
}

// ------------- CSR build: one block (512 thr) per graph, all in LDS ---------

__global__ __launch_bounds__(512) void csr_build(
        const int* __restrict__ ei, int E, int NPG, int EPG_NL,
        int* __restrict__ roff, int* __restrict__ csrc) {
    __shared__ int deg[512], buf[512], soff[512], cnt[512];
    int g = blockIdx.x, tid = threadIdx.x;
    int nb = g * NPG;
    int eb = g * EPG_NL;
    const int EPG = EPG_NL + NPG;
    deg[tid] = 1;                      // self loop
    __syncthreads();
    for (int i = tid; i < EPG_NL; i += 512)
        atomicAdd(&deg[ei[E + eb + i] - nb], 1);
    __syncthreads();
    buf[tid] = deg[tid];
    __syncthreads();
    #pragma unroll
    for (int ofs = 1; ofs < 512; ofs <<= 1) {
        int t = (tid >= ofs) ? buf[tid - ofs] : 0;
        __syncthreads();
        buf[tid] += t;
        __syncthreads();
    }
    int oe = buf[tid] - deg[tid];
    soff[tid] = oe;
    roff[nb + tid] = g * EPG + oe;
    if (tid == 511) roff[nb + 512] = g * EPG + buf[511];
    cnt[tid] = 1;
    csrc[g * EPG + oe] = nb + tid;
    __syncthreads();
    for (int i = tid; i < EPG_NL; i += 512) {
        int dl = ei[E + eb + i] - nb;
        int s  = ei[eb + i];
        int pos = atomicAdd(&cnt[dl], 1);
        csrc[g * EPG + soff[dl] + pos] = s;
    }
}

// All 4 weights: W [K][Nc] fp32 -> Wt [Nc][K] bf16 (transpose+cast), one launch.
__global__ __launch_bounds__(256) void tcast4_kernel(
        const float* __restrict__ Wl1, const float* __restrict__ Wr1,
        const float* __restrict__ Wl2, const float* __restrict__ Wr2,
        unsigned short* __restrict__ wc1, unsigned short* __restrict__ wc2) {
    int z = blockIdx.z;
    int Nc = (z < 2) ? 512 : 256;
    if (blockIdx.x * 32 >= Nc) return;
    const float* W = (z == 0) ? Wl1 : (z == 1) ? Wr1 : (z == 2) ? Wl2 : Wr2;
    unsigned short* th = (z == 0) ? wc1 : (z == 1) ? wc1 + 512 * 512
                       : (z == 2) ? wc2 : wc2 + 256 * 512;
    const int K = 512;
    __shared__ float t[32][33];
    int bx = blockIdx.x, by = blockIdx.y;
    int lx = threadIdx.x & 31, ly = threadIdx.x >> 5;
    #pragma unroll
    for (int r = ly; r < 32; r += 8)
        t[r][lx] = W[(size_t)(by * 32 + r) * Nc + bx * 32 + lx];
    __syncthreads();
    #pragma unroll
    for (int r = ly; r < 32; r += 8)
        th[(size_t)(bx * 32 + r) * K + by * 32 + lx] = f2bf_rn(t[lx][r]);
}

// bias concat: bcat1 = [bl1|br1] (1024), bcat2 = [bl2|br2] (512)
__global__ __launch_bounds__(512) void bconcat_kernel(
        const float* __restrict__ bl1, const float* __restrict__ br1,
        const float* __restrict__ bl2, const float* __restrict__ br2,
        float* __restrict__ bcat1, float* __restrict__ bcat2) {
    int i = blockIdx.x * 512 + threadIdx.x;
    if (i < 512)        bcat1[i] = bl1[i];
    else if (i < 1024)  bcat1[i] = br1[i - 512];
    else if (i < 1280)  bcat2[i - 1024] = bl2[i - 1024];
    else if (i < 1536)  bcat2[i - 1024] = br2[i - 1280];
}

// ---- L1 GEMM: 128x128, 4 waves, A fp32 reg-staged (2-deep) -> bf16 LDS ----
// C(bf16) = bf16(A_fp32)@B^T + bias. B bf16 [Nc][K] via global_load_lds.
// Iter t: load A(t+2) -> free reg set; pack+write A(t+1) (full-iter-old regs)
// BEFORE the MFMA cluster; B(t+1) DMA issued early. One barrier per K-tile.

__global__ __launch_bounds__(256) void gemm128f(
        const float* __restrict__ A,
        const unsigned short* __restrict__ B,
        const float* __restrict__ bias, unsigned short* __restrict__ C,
        int M, int K, int Nc) {
    constexpr int BUF = 16384;                  // A(8KB) | B(8KB)
    __shared__ __align__(16) char smem[2 * BUF];

    int tid  = threadIdx.x;
    int wave = tid >> 6, lane = tid & 63;
    int wr = wave >> 1, wc = wave & 1;

    int bx = blockIdx.x, by = blockIdx.y;
    if ((gridDim.y & 7) == 0) {                 // XCD swizzle
        int d = blockIdx.y * gridDim.x + blockIdx.x;
        int x = d & 7, i = d >> 3;
        by = (i / gridDim.x) * 8 + x;
        bx = i % gridDim.x;
    }
    int m0 = by * 128, n0 = bx * 128;

    // B DMA staging (2 loads cover the 8KB B tile)
    const unsigned short* gsrcB[2];
    int loffB[2];
    #pragma unroll
    for (int q = 0; q < 2; ++q) {
        int o    = q * 4096 + tid * 16;
        int row  = o >> 6;
        int slot = (o >> 4) & 3;
        int sl   = slot ^ ((row >> 1) & 3);
        gsrcB[q] = B + (size_t)(n0 + row) * K + sl * 8;
        loffB[q] = 8192 + q * 4096 + wave * 1024;
    }
    // A coalesced reg staging: load q covers fp32 bytes [q*4096+tid*16, +16)
    const float* asrcA[4];
    int awoff[4];
    #pragma unroll
    for (int q = 0; q < 4; ++q) {
        int o    = q * 4096 + tid * 16;         // fp32 tile byte offset (16KB)
        int row  = o >> 7;                      // 128B per fp32 row
        int fb   = o & 127;                     // in-row fp32 byte
        int bcol = fb >> 1;                     // in-row bf16 byte (0..63)
        int sl   = (bcol >> 4) ^ ((row >> 1) & 3);
        asrcA[q] = A + (size_t)(m0 + row) * K + (fb >> 2);
        awoff[q] = row * 64 + sl * 16 + (bcol & 8);
    }

    f32x4 acc[4][4];
    #pragma unroll
    for (int i = 0; i < 4; ++i)
        #pragma unroll
        for (int j = 0; j < 4; ++j) acc[i][j] = (f32x4){0.f, 0.f, 0.f, 0.f};

    int r = lane & 15, g = lane >> 4;
    int sw = (g ^ ((r >> 1) & 3)) * 16;

    const int NT = K >> 5;
    float4 rgA[4], rgB[4];                      // 2-deep A reg pipeline

    // prologue: A(0)->rgA, pack->buf0; B(0) DMA; A(1)->rgB
    #pragma unroll
    for (int q = 0; q < 4; ++q) { rgA[q] = *(const float4*)asrcA[q]; asrcA[q] += 32; }
    #pragma unroll
    for (int q = 0; q < 2; ++q) {
        __builtin_amdgcn_global_load_lds(
            (const __attribute__((address_space(1))) void*)(gsrcB[q]),
            (__attribute__((address_space(3))) void*)(smem + loffB[q]), 16, 0, 0);
        gsrcB[q] += 32;
    }
    #pragma unroll
    for (int q = 0; q < 4; ++q) { rgB[q] = *(const float4*)asrcA[q]; asrcA[q] += 32; }
    #pragma unroll
    for (int q = 0; q < 4; ++q) {
        ushort4 p;
        p.x = f2bf_rn(rgA[q].x); p.y = f2bf_rn(rgA[q].y);
        p.z = f2bf_rn(rgA[q].z); p.w = f2bf_rn(rgA[q].w);
        *(ushort4*)(smem + awoff[q]) = p;
    }
    __syncthreads();

    int cur = 0;
    for (int t = 0; t < NT; ++t) {
        bool haveN1 = (t + 1 < NT);
        // load A(t+2) into the set freed last iteration (static 2-phase)
        if (t + 2 < NT) {
            if ((t & 1) == 0) {
                #pragma unroll
                for (int q = 0; q < 4; ++q) { rgA[q] = *(const float4*)asrcA[q]; asrcA[q] += 32; }
            } else {
                #pragma unroll
                for (int q = 0; q < 4; ++q) { rgB[q] = *(const float4*)asrcA[q]; asrcA[q] += 32; }
            }
        }
        if (haveN1) {
            // B(t+1) DMA into other buffer
            #pragma unroll
            for (int q = 0; q < 2; ++q) {
                __builtin_amdgcn_global_load_lds(
                    (const __attribute__((address_space(1))) void*)(gsrcB[q]),
                    (__attribute__((address_space(3))) void*)(smem + loffB[q] + (cur ^ BUF)),
                    16, 0, 0);
                gsrcB[q] += 32;
            }
            // pack+write A(t+1) (regs loaded a full iteration ago) BEFORE MFMA
            if ((t & 1) == 0) {
                #pragma unroll
                for (int q = 0; q < 4; ++q) {
                    ushort4 p;
                    p.x = f2bf_rn(rgB[q].x); p.y = f2bf_rn(rgB[q].y);
                    p.z = f2bf_rn(rgB[q].z); p.w = f2bf_rn(rgB[q].w);
                    *(ushort4*)(smem + (cur ^ BUF) + awoff[q]) = p;
                }
            } else {
                #pragma unroll
                for (int q = 0; q < 4; ++q) {
                    ushort4 p;
                    p.x = f2bf_rn(rgA[q].x); p.y = f2bf_rn(rgA[q].y);
                    p.z = f2bf_rn(rgA[q].z); p.w = f2bf_rn(rgA[q].w);
                    *(ushort4*)(smem + (cur ^ BUF) + awoff[q]) = p;
                }
            }
        }
        const char* sb = smem + cur;
        bf16x8 a[4], b[4];
        #pragma unroll
        for (int i = 0; i < 4; ++i) {
            int offA = (wr * 64 + i * 16 + r) * 64 + sw;
            int offB = (wc * 64 + i * 16 + r) * 64 + sw;
            a[i] = *(const bf16x8*)(sb + offA);
            b[i] = *(const bf16x8*)(sb + 8192 + offB);
        }
        __builtin_amdgcn_s_setprio(1);
        #pragma unroll
        for (int i = 0; i < 4; ++i)
            #pragma unroll
            for (int j = 0; j < 4; ++j)
                acc[i][j] = __builtin_amdgcn_mfma_f32_16x16x32_bf16(a[i], b[j], acc[i][j], 0, 0, 0);
        __builtin_amdgcn_s_setprio(0);
        __syncthreads();
        cur ^= BUF;
    }

    #pragma unroll
    for (int j = 0; j < 4; ++j) {
        int col = n0 + wc * 64 + j * 16 + r;
        float bv = bias[col];
        #pragma unroll
        for (int i = 0; i < 4; ++i) {
            int rowb = m0 + wr * 64 + i * 16 + g * 4;
            #pragma unroll
            for (int t = 0; t < 4; ++t)
                C[(size_t)(rowb + t) * Nc + col] = f2bf_rn(acc[i][j][t] + bv);
        }
    }
}

// ---- L2 GEMM: 128x128, 4 waves, pure bf16 A/B via DMA ----

__global__ __launch_bounds__(256) void gemm128b(
        const unsigned short* __restrict__ A,
        const unsigned short* __restrict__ B,
        const float* __restrict__ bias, unsigned short* __restrict__ C,
        int M, int K, int Nc) {
    constexpr int NQ  = 4;
    constexpr int BUF = 16384;
    __shared__ __align__(16) char smem[2 * BUF];

    int tid  = threadIdx.x;
    int wave = tid >> 6, lane = tid & 63;
    int wr = wave >> 1, wc = wave & 1;

    int bx = blockIdx.x, by = blockIdx.y;
    if ((gridDim.y & 7) == 0) {
        int d = blockIdx.y * gridDim.x + blockIdx.x;
        int x = d & 7, i = d >> 3;
        by = (i / gridDim.x) * 8 + x;
        bx = i % gridDim.x;
    }
    int m0 = by * 128, n0 = bx * 128;

    const unsigned short* gsrc[NQ];
    int loff[NQ];
    #pragma unroll
    for (int q = 0; q < NQ; ++q) {
        int o    = q * 4096 + tid * 16;
        int tile = o >> 13;
        int ot   = o & 8191;
        int row  = ot >> 6;
        int slot = (ot >> 4) & 3;
        int sl   = slot ^ ((row >> 1) & 3);
        const unsigned short* base =
            (tile == 0) ? (A + (size_t)(m0 + row) * K)
                        : (B + (size_t)(n0 + row) * K);
        gsrc[q] = base + sl * 8;
        loff[q] = q * 4096 + wave * 1024;
    }

    f32x4 acc[4][4];
    #pragma unroll
    for (int i = 0; i < 4; ++i)
        #pragma unroll
        for (int j = 0; j < 4; ++j) acc[i][j] = (f32x4){0.f, 0.f, 0.f, 0.f};

    int r = lane & 15, g = lane >> 4;
    int sw = (g ^ ((r >> 1) & 3)) * 16;

    #pragma unroll
    for (int q = 0; q < NQ; ++q) {
        __builtin_amdgcn_global_load_lds(
            (const __attribute__((address_space(1))) void*)(gsrc[q]),
            (__attribute__((address_space(3))) void*)(smem + loff[q]), 16, 0, 0);
        gsrc[q] += 32;
    }
    __syncthreads();

    const int NT = K >> 5;
    int cur = 0;
    for (int t = 0; t < NT; ++t) {
        if (t + 1 < NT) {
            #pragma unroll
            for (int q = 0; q < NQ; ++q) {
                __builtin_amdgcn_global_load_lds(
                    (const __attribute__((address_space(1))) void*)(gsrc[q]),
                    (__attribute__((address_space(3))) void*)(smem + loff[q] + (cur ^ BUF)),
                    16, 0, 0);
                gsrc[q] += 32;
            }
        }
        const char* sb = smem + cur;
        bf16x8 a[4], b[4];
        #pragma unroll
        for (int i = 0; i < 4; ++i) {
            int offA = (wr * 64 + i * 16 + r) * 64 + sw;
            int offB = (wc * 64 + i * 16 + r) * 64 + sw;
            a[i] = *(const bf16x8*)(sb + offA);
            b[i] = *(const bf16x8*)(sb + 8192 + offB);
        }
        __builtin_amdgcn_s_setprio(1);
        #pragma unroll
        for (int i = 0; i < 4; ++i)
            #pragma unroll
            for (int j = 0; j < 4; ++j)
                acc[i][j] = __builtin_amdgcn_mfma_f32_16x16x32_bf16(a[i], b[j], acc[i][j], 0, 0, 0);
        __builtin_amdgcn_s_setprio(0);
        __syncthreads();
        cur ^= BUF;
    }

    #pragma unroll
    for (int j = 0; j < 4; ++j) {
        int col = n0 + wc * 64 + j * 16 + r;
        float bv = bias[col];
        #pragma unroll
        for (int i = 0; i < 4; ++i) {
            int rowb = m0 + wr * 64 + i * 16 + g * 4;
            #pragma unroll
            for (int t = 0; t < 4; ++t)
                C[(size_t)(rowb + t) * Nc + col] = f2bf_rn(acc[i][j][t] + bv);
        }
    }
}

// -------- XCD swizzle for edge kernels: graph g -> XCD g%8 --------

__device__ __forceinline__ int edge_blk_swz(int blk, int swz) {
    if (swz) {
        int x = blk & 7, i = blk >> 3;
        blk = (i >> 7) * 1024 + x * 128 + (i & 127);
    }
    return blk;
}

// ---------------- Layer 1 edge kernel: wave per node, 8 ch/lane ----------------

__global__ __launch_bounds__(256) void gat_edge1(
        const unsigned short* __restrict__ xlr,
        const float* __restrict__ att, const float* __restrict__ bias,
        const int* __restrict__ roff, const int* __restrict__ csrc,
        unsigned short* __restrict__ Hh, int chunkN, int n0, int swz) {
    int blk = edge_blk_swz(blockIdx.x, swz);
    int node = blk * 4 + (threadIdx.x >> 6);
    if (node >= chunkN) return;
    int lane = threadIdx.x & 63;
    int bc = lane * 8;                 // head = lane/16
    float xrv[8], att6[8], att4[8];
    {
        uint4 t0 = *(const uint4*)&xlr[(size_t)node * 1024 + 512 + bc];
        const unsigned* u = (const unsigned*)&t0;
        #pragma unroll
        for (int j = 0; j < 4; ++j) {
            xrv[2*j]   = __uint_as_float(u[j] << 16);
            xrv[2*j+1] = __uint_as_float(u[j] & 0xFFFF0000u);
        }
        float4 a0 = *(const float4*)&att[bc];
        float4 a1 = *(const float4*)&att[bc + 4];
        float av[8] = {a0.x, a0.y, a0.z, a0.w, a1.x, a1.y, a1.z, a1.w};
        #pragma unroll
        for (int k = 0; k < 8; ++k) { att6[k] = 0.6f * av[k]; att4[k] = 0.4f * av[k]; }
    }
    float acc[8];
    float m = 0.0f, d = 0.0f;
    int e0 = roff[n0 + node], e1 = roff[n0 + node + 1];
    uint4 cv;
    {
        int s = csrc[e0] - n0;
        cv = *(const uint4*)&xlr[(size_t)s * 1024 + bc];
    }
    for (int e = e0; e < e1; ++e) {
        float xv[8];
        {
            const unsigned* u = (const unsigned*)&cv;
            #pragma unroll
            for (int j = 0; j < 4; ++j) {
                xv[2*j]   = __uint_as_float(u[j] << 16);
                xv[2*j+1] = __uint_as_float(u[j] & 0xFFFF0000u);
            }
        }
        if (e + 1 < e1) {              // prefetch next edge
            int s2 = csrc[e + 1] - n0;
            cv = *(const uint4*)&xlr[(size_t)s2 * 1024 + bc];
        }
        float p = 0.0f;
        #pragma unroll
        for (int k = 0; k < 8; ++k) {
            float t = xv[k] + xrv[k];
            p = fmaf(att6[k], t, p);
            p = fmaf(att4[k], fabsf(t), p);    // leaky = 0.6t + 0.4|t|
        }
        p += __shfl_xor(p, 1); p += __shfl_xor(p, 2);
        p += __shfl_xor(p, 4); p += __shfl_xor(p, 8);
        if (e == e0) {
            m = p; d = 1.0f;
            #pragma unroll
            for (int k = 0; k < 8; ++k) acc[k] = xv[k];
        } else if (p > m + 8.0f) {
            float sc = __expf(m - p);
            d = fmaf(d, sc, 1.0f);
            #pragma unroll
            for (int k = 0; k < 8; ++k) acc[k] = fmaf(acc[k], sc, xv[k]);
            m = p;
        } else {
            float w = __expf(p - m);
            d += w;
            #pragma unroll
            for (int k = 0; k < 8; ++k) acc[k] = fmaf(w, xv[k], acc[k]);
        }
    }
    float inv = 1.0f / d;
    ushort8 hv;
    #pragma unroll
    for (int k = 0; k < 8; ++k)
        ((unsigned short*)&hv)[k] = f2bf_rn(fmaf(acc[k], inv, bias[bc + k]));
    *(ushort8*)&Hh[(size_t)node * 512 + bc] = hv;
}

// ------- Layer 2 edge kernel: fused head-mean + feature-mean, 4 ch/lane -------

__global__ __launch_bounds__(256) void gat_edge2(
        const unsigned short* __restrict__ xlr,
        const float* __restrict__ att, const float* __restrict__ bias,
        const int* __restrict__ roff, const int* __restrict__ csrc,
        float* __restrict__ out, int chunkN, int n0, int swz) {
    int blk = edge_blk_swz(blockIdx.x, swz);
    int node = blk * 4 + (threadIdx.x >> 6);
    if (node >= chunkN) return;
    int lane = threadIdx.x & 63;
    int bc = lane * 4;                 // within [0,256); head = lane/16
    float xrv[4], att6[4], att4[4];
    {
        uint2 t0 = *(const uint2*)&xlr[(size_t)node * 512 + 256 + bc];
        const unsigned* u = (const unsigned*)&t0;
        #pragma unroll
        for (int j = 0; j < 2; ++j) {
            xrv[2*j]   = __uint_as_float(u[j] << 16);
            xrv[2*j+1] = __uint_as_float(u[j] & 0xFFFF0000u);
        }
        float4 a0 = *(const float4*)&att[bc];
        float av[4] = {a0.x, a0.y, a0.z, a0.w};
        #pragma unroll
        for (int k = 0; k < 4; ++k) { att6[k] = 0.6f * av[k]; att4[k] = 0.4f * av[k]; }
    }
    float acc[4];
    float m = 0.0f, d = 0.0f;
    int e0 = roff[n0 + node], e1 = roff[n0 + node + 1];
    uint2 cv;
    {
        int s = csrc[e0] - n0;
        cv = *(const uint2*)&xlr[(size_t)s * 512 + bc];
    }
    for (int e = e0; e < e1; ++e) {
        float xv[4];
        {
            const unsigned* u = (const unsigned*)&cv;
            #pragma unroll
            for (int j = 0; j < 2; ++j) {
                xv[2*j]   = __uint_as_float(u[j] << 16);
                xv[2*j+1] = __uint_as_float(u[j] & 0xFFFF0000u);
            }
        }
        if (e + 1 < e1) {
            int s2 = csrc[e + 1] - n0;
            cv = *(const uint2*)&xlr[(size_t)s2 * 512 + bc];
        }
        float p = 0.0f;
        #pragma unroll
        for (int k = 0; k < 4; ++k) {
            float t = xv[k] + xrv[k];
            p = fmaf(att6[k], t, p);
            p = fmaf(att4[k], fabsf(t), p);
        }
        p += __shfl_xor(p, 1); p += __shfl_xor(p, 2);
        p += __shfl_xor(p, 4); p += __shfl_xor(p, 8);
        if (e == e0) {
            m = p; d = 1.0f;
            #pragma unroll
            for (int k = 0; k < 4; ++k) acc[k] = xv[k];
        } else if (p > m + 8.0f) {
            float sc = __expf(m - p);
            d = fmaf(d, sc, 1.0f);
            #pragma unroll
            for (int k = 0; k < 4; ++k) acc[k] = fmaf(acc[k], sc, xv[k]);
            m = p;
        } else {
            float w = __expf(p - m);
            d += w;
            #pragma unroll
            for (int k = 0; k < 4; ++k) acc[k] = fmaf(w, xv[k], acc[k]);
        }
    }
    float inv = 1.0f / d;
    float v[4];
    #pragma unroll
    for (int k = 0; k < 4; ++k) v[k] = acc[k] * inv;
    #pragma unroll
    for (int k = 0; k < 4; ++k) {
        v[k] += __shfl_xor(v[k], 16);
        v[k] += __shfl_xor(v[k], 32);
    }
    int cb = (lane & 15) * 4;
    float s = 0.25f * (v[0] + v[1] + v[2] + v[3])
            + bias[cb] + bias[cb + 1] + bias[cb + 2] + bias[cb + 3];
    s += __shfl_xor(s, 1); s += __shfl_xor(s, 2);
    s += __shfl_xor(s, 4); s += __shfl_xor(s, 8);
    if (lane == 0) out[node] = s * (1.0f / 64.0f);
}

// ---------------- launch ----------------

extern "C" void kernel_launch(void* const* d_in, const int* in_sizes, int n_in,
                              void* d_out, int out_size, void* d_ws, size_t ws_size,
                              hipStream_t stream) {
    const float* x    = (const float*)d_in[0];
    const int*   ei   = (const int*)d_in[1];
    const float* Wl1  = (const float*)d_in[3];
    const float* bl1  = (const float*)d_in[4];
    const float* Wr1  = (const float*)d_in[5];
    const float* br1  = (const float*)d_in[6];
    const float* att1 = (const float*)d_in[7];
    const float* bias1= (const float*)d_in[8];
    const float* Wl2  = (const float*)d_in[9];
    const float* bl2  = (const float*)d_in[10];
    const float* Wr2  = (const float*)d_in[11];
    const float* br2  = (const float*)d_in[12];
    const float* att2 = (const float*)d_in[13];
    const float* bias2= (const float*)d_in[14];
    float* out = (float*)d_out;

    const int F = 512;
    const int N = in_sizes[0] / F;        // 32768
    const int E = in_sizes[1] / 2;        // 262144
    const int NG = 64;
    const int NPG = N / NG;               // 512
    const int EPG_NL = E / NG;            // 4096 non-loop edges per graph

    char* w = (char*)d_ws;
    int* roff = (int*)(w);                                   // N+1
    int* csrc = (int*)(w + 0x80000);                         // E+N
    unsigned short* wc1 = (unsigned short*)(w + 0x200000);   // [1024][512] bf16
    unsigned short* wc2 = (unsigned short*)(w + 0x400000);   // [512][512] bf16
    float* bcat1 = (float*)(w + 0x500000);
    float* bcat2 = (float*)(w + 0x501000);
    const size_t HDR = 6ull << 20;

    int chunkG = NG;
    while (chunkG > 1) {
        size_t need = HDR + 3ull * (size_t)chunkG * NPG * 512 * 4;
        if (need <= ws_size) break;
        chunkG >>= 1;
    }
    const int chunkN = chunkG * NPG;
    const size_t BSZ = (size_t)chunkN * 512 * 4;
    char* R1 = w + HDR;
    char* R2 = w + HDR + BSZ;
    const int swz = (chunkG % 8 == 0) ? 1 : 0;

    csr_build<<<NG, 512, 0, stream>>>(ei, E, NPG, EPG_NL, roff, csrc);
    tcast4_kernel<<<dim3(16, 16, 4), 256, 0, stream>>>(Wl1, Wr1, Wl2, Wr2, wc1, wc2);
    bconcat_kernel<<<3, 512, 0, stream>>>(bl1, br1, bl2, br2, bcat1, bcat2);

    for (int g0 = 0; g0 < NG; g0 += chunkG) {
        int n0 = g0 * NPG;
        const float* xc = x + (size_t)n0 * 512;
        unsigned short* xlr1 = (unsigned short*)R2;  // bf16 [chunkN][1024]
        unsigned short* Hh   = (unsigned short*)R1;  // bf16 [chunkN][512]
        unsigned short* xlr2 = (unsigned short*)R2;  // bf16 [chunkN][512]

        gemm128f<<<dim3(1024/128, chunkN/128), 256, 0, stream>>>(
            xc, wc1, bcat1, xlr1, chunkN, 512, 1024);
        gat_edge1<<<(chunkN * 64) / 256, 256, 0, stream>>>(
            xlr1, att1, bias1, roff, csrc, Hh, chunkN, n0, swz);

        gemm128b<<<dim3(512/128, chunkN/128), 256, 0, stream>>>(
            Hh, wc2, bcat2, xlr2, chunkN, 512, 512);
        gat_edge2<<<(chunkN * 64) / 256, 256, 0, stream>>>(
            xlr2, att2, bias2, roff, csrc, out + n0, chunkN, n0, swz);
    }
}

// Round 22
// 176.445 us; speedup vs baseline: 1.0446x; 1.0446x over previous
//
#include <hip/hip_runtime.h>
#include <hip/hip_bf16.h>

// GATv2 2-layer GNN. Round 22: REVERT to round-18 configuration (best stable:
// separate cast_hi pass + all-DMA 128^2 bf16 GEMM for both layers), keeping
// fused CSR/tcast4/bconcat and the defer-max edge kernels. The fused-cast L1
// GEMM (rounds 19-21: 86/80/96 us) lost to split cast+GEMM (16+53 us) because
// the GEMM grid re-reads A 8x - cheap via L2 as a separate pass, expensive as
// per-block reg-staging latency.
// N=32768 (64 graphs x 512), F=512, E=262144 (+N self loops), H=4, C1=128, C2=64.

typedef __bf16 bf16_t;
typedef bf16_t bf16x8 __attribute__((ext_vector_type(8)));
typedef float f32x4 __attribute__((ext_vector_type(4)));
typedef unsigned short ushort8 __attribute__((ext_vector_type(8)));

__device__ __forceinline__ unsigned short f2bf_rn(float f) {
    unsigned u = __float_as_uint(f);
    unsigned r = (u + 0x7FFFu + ((u >> 16) & 1u)) >> 16;
    return (unsigned short)r;
}

// ------------- CSR build: one block (512 thr) per graph, all in LDS ---------

__global__ __launch_bounds__(512) void csr_build(
        const int* __restrict__ ei, int E, int NPG, int EPG_NL,
        int* __restrict__ roff, int* __restrict__ csrc) {
    __shared__ int deg[512], buf[512], soff[512], cnt[512];
    int g = blockIdx.x, tid = threadIdx.x;
    int nb = g * NPG;
    int eb = g * EPG_NL;
    const int EPG = EPG_NL + NPG;
    deg[tid] = 1;                      // self loop
    __syncthreads();
    for (int i = tid; i < EPG_NL; i += 512)
        atomicAdd(&deg[ei[E + eb + i] - nb], 1);
    __syncthreads();
    buf[tid] = deg[tid];
    __syncthreads();
    #pragma unroll
    for (int ofs = 1; ofs < 512; ofs <<= 1) {
        int t = (tid >= ofs) ? buf[tid - ofs] : 0;
        __syncthreads();
        buf[tid] += t;
        __syncthreads();
    }
    int oe = buf[tid] - deg[tid];
    soff[tid] = oe;
    roff[nb + tid] = g * EPG + oe;
    if (tid == 511) roff[nb + 512] = g * EPG + buf[511];
    cnt[tid] = 1;
    csrc[g * EPG + oe] = nb + tid;
    __syncthreads();
    for (int i = tid; i < EPG_NL; i += 512) {
        int dl = ei[E + eb + i] - nb;
        int s  = ei[eb + i];
        int pos = atomicAdd(&cnt[dl], 1);
        csrc[g * EPG + soff[dl] + pos] = s;
    }
}

// ---------------- fp32 -> bf16 cast (hi only) ----------------

__global__ __launch_bounds__(256) void cast_hi_kernel(
        const float* __restrict__ X, unsigned short* __restrict__ hi, int n4) {
    for (int i = blockIdx.x * blockDim.x + threadIdx.x; i < n4;
         i += gridDim.x * blockDim.x) {
        float4 v = ((const float4*)X)[i];
        ushort4 h;
        h.x = f2bf_rn(v.x); h.y = f2bf_rn(v.y);
        h.z = f2bf_rn(v.z); h.w = f2bf_rn(v.w);
        ((ushort4*)hi)[i] = h;
    }
}

// All 4 weights: W [K][Nc] fp32 -> Wt [Nc][K] bf16 (transpose+cast), one launch.
__global__ __launch_bounds__(256) void tcast4_kernel(
        const float* __restrict__ Wl1, const float* __restrict__ Wr1,
        const float* __restrict__ Wl2, const float* __restrict__ Wr2,
        unsigned short* __restrict__ wc1, unsigned short* __restrict__ wc2) {
    int z = blockIdx.z;
    int Nc = (z < 2) ? 512 : 256;
    if (blockIdx.x * 32 >= Nc) return;
    const float* W = (z == 0) ? Wl1 : (z == 1) ? Wr1 : (z == 2) ? Wl2 : Wr2;
    unsigned short* th = (z == 0) ? wc1 : (z == 1) ? wc1 + 512 * 512
                       : (z == 2) ? wc2 : wc2 + 256 * 512;
    const int K = 512;
    __shared__ float t[32][33];
    int bx = blockIdx.x, by = blockIdx.y;
    int lx = threadIdx.x & 31, ly = threadIdx.x >> 5;
    #pragma unroll
    for (int r = ly; r < 32; r += 8)
        t[r][lx] = W[(size_t)(by * 32 + r) * Nc + bx * 32 + lx];
    __syncthreads();
    #pragma unroll
    for (int r = ly; r < 32; r += 8)
        th[(size_t)(bx * 32 + r) * K + by * 32 + lx] = f2bf_rn(t[lx][r]);
}

// bias concat: bcat1 = [bl1|br1] (1024), bcat2 = [bl2|br2] (512)
__global__ __launch_bounds__(512) void bconcat_kernel(
        const float* __restrict__ bl1, const float* __restrict__ br1,
        const float* __restrict__ bl2, const float* __restrict__ br2,
        float* __restrict__ bcat1, float* __restrict__ bcat2) {
    int i = blockIdx.x * 512 + threadIdx.x;
    if (i < 512)        bcat1[i] = bl1[i];
    else if (i < 1024)  bcat1[i] = br1[i - 512];
    else if (i < 1280)  bcat2[i - 1024] = bl2[i - 1024];
    else if (i < 1536)  bcat2[i - 1024] = br2[i - 1280];
}

// ---- 128x128 GEMM, 4 waves, pure bf16, 2-buffer dbuf (32KB -> 5 blk/CU) ----

__global__ __launch_bounds__(256) void gemm128b(
        const unsigned short* __restrict__ A,
        const unsigned short* __restrict__ B,
        const float* __restrict__ bias, unsigned short* __restrict__ C,
        int M, int K, int Nc) {
    constexpr int NQ  = 4;
    constexpr int BUF = 16384;
    __shared__ __align__(16) char smem[2 * BUF];

    int tid  = threadIdx.x;
    int wave = tid >> 6, lane = tid & 63;
    int wr = wave >> 1, wc = wave & 1;

    int bx = blockIdx.x, by = blockIdx.y;
    if ((gridDim.y & 7) == 0) {                 // XCD swizzle
        int d = blockIdx.y * gridDim.x + blockIdx.x;
        int x = d & 7, i = d >> 3;
        by = (i / gridDim.x) * 8 + x;
        bx = i % gridDim.x;
    }
    int m0 = by * 128, n0 = bx * 128;

    const unsigned short* gsrc[NQ];
    int loff[NQ];
    #pragma unroll
    for (int q = 0; q < NQ; ++q) {
        int o    = q * 4096 + tid * 16;
        int tile = o >> 13;
        int ot   = o & 8191;
        int row  = ot >> 6;
        int slot = (ot >> 4) & 3;
        int sl   = slot ^ ((row >> 1) & 3);
        const unsigned short* base =
            (tile == 0) ? (A + (size_t)(m0 + row) * K)
                        : (B + (size_t)(n0 + row) * K);
        gsrc[q] = base + sl * 8;
        loff[q] = q * 4096 + wave * 1024;
    }

    f32x4 acc[4][4];
    #pragma unroll
    for (int i = 0; i < 4; ++i)
        #pragma unroll
        for (int j = 0; j < 4; ++j) acc[i][j] = (f32x4){0.f, 0.f, 0.f, 0.f};

    int r = lane & 15, g = lane >> 4;
    int sw = (g ^ ((r >> 1) & 3)) * 16;

    #pragma unroll
    for (int q = 0; q < NQ; ++q) {
        __builtin_amdgcn_global_load_lds(
            (const __attribute__((address_space(1))) void*)(gsrc[q]),
            (__attribute__((address_space(3))) void*)(smem + loff[q]), 16, 0, 0);
        gsrc[q] += 32;
    }
    __syncthreads();

    const int NT = K >> 5;
    int cur = 0;
    for (int t = 0; t < NT; ++t) {
        if (t + 1 < NT) {
            #pragma unroll
            for (int q = 0; q < NQ; ++q) {
                __builtin_amdgcn_global_load_lds(
                    (const __attribute__((address_space(1))) void*)(gsrc[q]),
                    (__attribute__((address_space(3))) void*)(smem + loff[q] + (cur ^ BUF)),
                    16, 0, 0);
                gsrc[q] += 32;
            }
        }
        const char* sb = smem + cur;
        bf16x8 a[4], b[4];
        #pragma unroll
        for (int i = 0; i < 4; ++i) {
            int offA = (wr * 64 + i * 16 + r) * 64 + sw;
            int offB = (wc * 64 + i * 16 + r) * 64 + sw;
            a[i] = *(const bf16x8*)(sb + offA);
            b[i] = *(const bf16x8*)(sb + 8192 + offB);
        }
        __builtin_amdgcn_s_setprio(1);
        #pragma unroll
        for (int i = 0; i < 4; ++i)
            #pragma unroll
            for (int j = 0; j < 4; ++j)
                acc[i][j] = __builtin_amdgcn_mfma_f32_16x16x32_bf16(a[i], b[j], acc[i][j], 0, 0, 0);
        __builtin_amdgcn_s_setprio(0);
        __syncthreads();
        cur ^= BUF;
    }

    #pragma unroll
    for (int j = 0; j < 4; ++j) {
        int col = n0 + wc * 64 + j * 16 + r;
        float bv = bias[col];
        #pragma unroll
        for (int i = 0; i < 4; ++i) {
            int rowb = m0 + wr * 64 + i * 16 + g * 4;
            #pragma unroll
            for (int t = 0; t < 4; ++t)
                C[(size_t)(rowb + t) * Nc + col] = f2bf_rn(acc[i][j][t] + bv);
        }
    }
}

// -------- XCD swizzle for edge kernels: graph g -> XCD g%8 --------

__device__ __forceinline__ int edge_blk_swz(int blk, int swz) {
    if (swz) {
        int x = blk & 7, i = blk >> 3;
        blk = (i >> 7) * 1024 + x * 128 + (i & 127);
    }
    return blk;
}

// ---------------- Layer 1 edge kernel: wave per node, 8 ch/lane ----------------

__global__ __launch_bounds__(256) void gat_edge1(
        const unsigned short* __restrict__ xlr,
        const float* __restrict__ att, const float* __restrict__ bias,
        const int* __restrict__ roff, const int* __restrict__ csrc,
        unsigned short* __restrict__ Hh, int chunkN, int n0, int swz) {
    int blk = edge_blk_swz(blockIdx.x, swz);
    int node = blk * 4 + (threadIdx.x >> 6);
    if (node >= chunkN) return;
    int lane = threadIdx.x & 63;
    int bc = lane * 8;                 // head = lane/16
    float xrv[8], att6[8], att4[8];
    {
        uint4 t0 = *(const uint4*)&xlr[(size_t)node * 1024 + 512 + bc];
        const unsigned* u = (const unsigned*)&t0;
        #pragma unroll
        for (int j = 0; j < 4; ++j) {
            xrv[2*j]   = __uint_as_float(u[j] << 16);
            xrv[2*j+1] = __uint_as_float(u[j] & 0xFFFF0000u);
        }
        float4 a0 = *(const float4*)&att[bc];
        float4 a1 = *(const float4*)&att[bc + 4];
        float av[8] = {a0.x, a0.y, a0.z, a0.w, a1.x, a1.y, a1.z, a1.w};
        #pragma unroll
        for (int k = 0; k < 8; ++k) { att6[k] = 0.6f * av[k]; att4[k] = 0.4f * av[k]; }
    }
    float acc[8];
    float m = 0.0f, d = 0.0f;
    int e0 = roff[n0 + node], e1 = roff[n0 + node + 1];
    uint4 cv;
    {
        int s = csrc[e0] - n0;
        cv = *(const uint4*)&xlr[(size_t)s * 1024 + bc];
    }
    for (int e = e0; e < e1; ++e) {
        float xv[8];
        {
            const unsigned* u = (const unsigned*)&cv;
            #pragma unroll
            for (int j = 0; j < 4; ++j) {
                xv[2*j]   = __uint_as_float(u[j] << 16);
                xv[2*j+1] = __uint_as_float(u[j] & 0xFFFF0000u);
            }
        }
        if (e + 1 < e1) {              // prefetch next edge
            int s2 = csrc[e + 1] - n0;
            cv = *(const uint4*)&xlr[(size_t)s2 * 1024 + bc];
        }
        float p = 0.0f;
        #pragma unroll
        for (int k = 0; k < 8; ++k) {
            float t = xv[k] + xrv[k];
            p = fmaf(att6[k], t, p);
            p = fmaf(att4[k], fabsf(t), p);    // leaky = 0.6t + 0.4|t|
        }
        p += __shfl_xor(p, 1); p += __shfl_xor(p, 2);
        p += __shfl_xor(p, 4); p += __shfl_xor(p, 8);
        if (e == e0) {
            m = p; d = 1.0f;
            #pragma unroll
            for (int k = 0; k < 8; ++k) acc[k] = xv[k];
        } else if (p > m + 8.0f) {
            float sc = __expf(m - p);
            d = fmaf(d, sc, 1.0f);
            #pragma unroll
            for (int k = 0; k < 8; ++k) acc[k] = fmaf(acc[k], sc, xv[k]);
            m = p;
        } else {
            float w = __expf(p - m);
            d += w;
            #pragma unroll
            for (int k = 0; k < 8; ++k) acc[k] = fmaf(w, xv[k], acc[k]);
        }
    }
    float inv = 1.0f / d;
    ushort8 hv;
    #pragma unroll
    for (int k = 0; k < 8; ++k)
        ((unsigned short*)&hv)[k] = f2bf_rn(fmaf(acc[k], inv, bias[bc + k]));
    *(ushort8*)&Hh[(size_t)node * 512 + bc] = hv;
}

// ------- Layer 2 edge kernel: fused head-mean + feature-mean, 4 ch/lane -------

__global__ __launch_bounds__(256) void gat_edge2(
        const unsigned short* __restrict__ xlr,
        const float* __restrict__ att, const float* __restrict__ bias,
        const int* __restrict__ roff, const int* __restrict__ csrc,
        float* __restrict__ out, int chunkN, int n0, int swz) {
    int blk = edge_blk_swz(blockIdx.x, swz);
    int node = blk * 4 + (threadIdx.x >> 6);
    if (node >= chunkN) return;
    int lane = threadIdx.x & 63;
    int bc = lane * 4;                 // within [0,256); head = lane/16
    float xrv[4], att6[4], att4[4];
    {
        uint2 t0 = *(const uint2*)&xlr[(size_t)node * 512 + 256 + bc];
        const unsigned* u = (const unsigned*)&t0;
        #pragma unroll
        for (int j = 0; j < 2; ++j) {
            xrv[2*j]   = __uint_as_float(u[j] << 16);
            xrv[2*j+1] = __uint_as_float(u[j] & 0xFFFF0000u);
        }
        float4 a0 = *(const float4*)&att[bc];
        float av[4] = {a0.x, a0.y, a0.z, a0.w};
        #pragma unroll
        for (int k = 0; k < 4; ++k) { att6[k] = 0.6f * av[k]; att4[k] = 0.4f * av[k]; }
    }
    float acc[4];
    float m = 0.0f, d = 0.0f;
    int e0 = roff[n0 + node], e1 = roff[n0 + node + 1];
    uint2 cv;
    {
        int s = csrc[e0] - n0;
        cv = *(const uint2*)&xlr[(size_t)s * 512 + bc];
    }
    for (int e = e0; e < e1; ++e) {
        float xv[4];
        {
            const unsigned* u = (const unsigned*)&cv;
            #pragma unroll
            for (int j = 0; j < 2; ++j) {
                xv[2*j]   = __uint_as_float(u[j] << 16);
                xv[2*j+1] = __uint_as_float(u[j] & 0xFFFF0000u);
            }
        }
        if (e + 1 < e1) {
            int s2 = csrc[e + 1] - n0;
            cv = *(const uint2*)&xlr[(size_t)s2 * 512 + bc];
        }
        float p = 0.0f;
        #pragma unroll
        for (int k = 0; k < 4; ++k) {
            float t = xv[k] + xrv[k];
            p = fmaf(att6[k], t, p);
            p = fmaf(att4[k], fabsf(t), p);
        }
        p += __shfl_xor(p, 1); p += __shfl_xor(p, 2);
        p += __shfl_xor(p, 4); p += __shfl_xor(p, 8);
        if (e == e0) {
            m = p; d = 1.0f;
            #pragma unroll
            for (int k = 0; k < 4; ++k) acc[k] = xv[k];
        } else if (p > m + 8.0f) {
            float sc = __expf(m - p);
            d = fmaf(d, sc, 1.0f);
            #pragma unroll
            for (int k = 0; k < 4; ++k) acc[k] = fmaf(acc[k], sc, xv[k]);
            m = p;
        } else {
            float w = __expf(p - m);
            d += w;
            #pragma unroll
            for (int k = 0; k < 4; ++k) acc[k] = fmaf(w, xv[k], acc[k]);
        }
    }
    float inv = 1.0f / d;
    float v[4];
    #pragma unroll
    for (int k = 0; k < 4; ++k) v[k] = acc[k] * inv;
    #pragma unroll
    for (int k = 0; k < 4; ++k) {
        v[k] += __shfl_xor(v[k], 16);
        v[k] += __shfl_xor(v[k], 32);
    }
    int cb = (lane & 15) * 4;
    float s = 0.25f * (v[0] + v[1] + v[2] + v[3])
            + bias[cb] + bias[cb + 1] + bias[cb + 2] + bias[cb + 3];
    s += __shfl_xor(s, 1); s += __shfl_xor(s, 2);
    s += __shfl_xor(s, 4); s += __shfl_xor(s, 8);
    if (lane == 0) out[node] = s * (1.0f / 64.0f);
}

// ---------------- launch ----------------

extern "C" void kernel_launch(void* const* d_in, const int* in_sizes, int n_in,
                              void* d_out, int out_size, void* d_ws, size_t ws_size,
                              hipStream_t stream) {
    const float* x    = (const float*)d_in[0];
    const int*   ei   = (const int*)d_in[1];
    const float* Wl1  = (const float*)d_in[3];
    const float* bl1  = (const float*)d_in[4];
    const float* Wr1  = (const float*)d_in[5];
    const float* br1  = (const float*)d_in[6];
    const float* att1 = (const float*)d_in[7];
    const float* bias1= (const float*)d_in[8];
    const float* Wl2  = (const float*)d_in[9];
    const float* bl2  = (const float*)d_in[10];
    const float* Wr2  = (const float*)d_in[11];
    const float* br2  = (const float*)d_in[12];
    const float* att2 = (const float*)d_in[13];
    const float* bias2= (const float*)d_in[14];
    float* out = (float*)d_out;

    const int F = 512;
    const int N = in_sizes[0] / F;        // 32768
    const int E = in_sizes[1] / 2;        // 262144
    const int NG = 64;
    const int NPG = N / NG;               // 512
    const int EPG_NL = E / NG;            // 4096 non-loop edges per graph

    char* w = (char*)d_ws;
    int* roff = (int*)(w);                                   // N+1
    int* csrc = (int*)(w + 0x80000);                         // E+N
    unsigned short* wc1 = (unsigned short*)(w + 0x200000);   // [1024][512] bf16
    unsigned short* wc2 = (unsigned short*)(w + 0x400000);   // [512][512] bf16
    float* bcat1 = (float*)(w + 0x500000);
    float* bcat2 = (float*)(w + 0x501000);
    const size_t HDR = 6ull << 20;

    int chunkG = NG;
    while (chunkG > 1) {
        size_t need = HDR + 3ull * (size_t)chunkG * NPG * 512 * 4;
        if (need <= ws_size) break;
        chunkG >>= 1;
    }
    const int chunkN = chunkG * NPG;
    const size_t BSZ = (size_t)chunkN * 512 * 4;
    char* R1 = w + HDR;
    char* R2 = w + HDR + BSZ;
    const int swz = (chunkG % 8 == 0) ? 1 : 0;

    csr_build<<<NG, 512, 0, stream>>>(ei, E, NPG, EPG_NL, roff, csrc);
    tcast4_kernel<<<dim3(16, 16, 4), 256, 0, stream>>>(Wl1, Wr1, Wl2, Wr2, wc1, wc2);
    bconcat_kernel<<<3, 512, 0, stream>>>(bl1, br1, bl2, br2, bcat1, bcat2);

    for (int g0 = 0; g0 < NG; g0 += chunkG) {
        int n0 = g0 * NPG;
        const float* xc = x + (size_t)n0 * 512;
        unsigned short* Xh   = (unsigned short*)R1;
        unsigned short* xlr1 = (unsigned short*)R2;  // bf16 [chunkN][1024]
        unsigned short* Hh   = (unsigned short*)R1;  // reuse (Xh dead after L1 gemm)
        unsigned short* xlr2 = (unsigned short*)R2;  // bf16 [chunkN][512]

        cast_hi_kernel<<<2048, 256, 0, stream>>>(xc, Xh, chunkN * 512 / 4);
        gemm128b<<<dim3(1024/128, chunkN/128), 256, 0, stream>>>(
            Xh, wc1, bcat1, xlr1, chunkN, 512, 1024);
        gat_edge1<<<(chunkN * 64) / 256, 256, 0, stream>>>(
            xlr1, att1, bias1, roff, csrc, Hh, chunkN, n0, swz);

        gemm128b<<<dim3(512/128, chunkN/128), 256, 0, stream>>>(
            Hh, wc2, bcat2, xlr2, chunkN, 512, 512);
        gat_edge2<<<(chunkN * 64) / 256, 256, 0, stream>>>(
            xlr2, att2, bias2, roff, csrc, out + n0, chunkN, n0, swz);
    }
}

// Round 23
// 166.885 us; speedup vs baseline: 1.1045x; 1.0573x over previous
//
#include <hip/hip_runtime.h>
#include <hip/hip_bf16.h>

// GATv2 2-layer GNN. Round 23: merge the 4 independent prep kernels
// (csr_build | tcast4 | bconcat | cast_hi) into ONE dispatch partitioned by
// blockIdx range (block-uniform branches) -> 8 dispatches become 5, cutting
// ~3 launch gaps. Compute kernels identical to round 22 (best stable config).
// N=32768 (64 graphs x 512), F=512, E=262144 (+N self loops), H=4, C1=128, C2=64.

typedef __bf16 bf16_t;
typedef bf16_t bf16x8 __attribute__((ext_vector_type(8)));
typedef float f32x4 __attribute__((ext_vector_type(4)));
typedef unsigned short ushort8 __attribute__((ext_vector_type(8)));

__device__ __forceinline__ unsigned short f2bf_rn(float f) {
    unsigned u = __float_as_uint(f);
    unsigned r = (u + 0x7FFFu + ((u >> 16) & 1u)) >> 16;
    return (unsigned short)r;
}

// ---------------- fused prep kernel ----------------
// blocks [0,64):        per-graph CSR build (LDS hist+scan+scatter)
// blocks [64,832):      weight transpose+cast (4 weights)
// blocks [832,835):     bias concat
// blocks [835,835+1024): x fp32 -> bf16 cast (grid-stride)

__global__ __launch_bounds__(512) void prep_kernel(
        const int* __restrict__ ei, int E, int NPG, int EPG_NL,
        int* __restrict__ roff, int* __restrict__ csrc,
        const float* __restrict__ Wl1, const float* __restrict__ Wr1,
        const float* __restrict__ Wl2, const float* __restrict__ Wr2,
        unsigned short* __restrict__ wc1, unsigned short* __restrict__ wc2,
        const float* __restrict__ bl1, const float* __restrict__ br1,
        const float* __restrict__ bl2, const float* __restrict__ br2,
        float* __restrict__ bcat1, float* __restrict__ bcat2,
        const float* __restrict__ X, unsigned short* __restrict__ Xh, int n4,
        int NG) {
    __shared__ int sh[2048];           // 8KB union
    int b = blockIdx.x, tid = threadIdx.x;

    if (b < NG) {
        // ---- CSR build for graph b ----
        int* deg  = sh;
        int* buf  = sh + 512;
        int* soff = sh + 1024;
        int* cnt  = sh + 1536;
        int g = b;
        int nb = g * NPG;
        int eb = g * EPG_NL;
        const int EPG = EPG_NL + NPG;
        deg[tid] = 1;                  // self loop
        __syncthreads();
        for (int i = tid; i < EPG_NL; i += 512)
            atomicAdd(&deg[ei[E + eb + i] - nb], 1);
        __syncthreads();
        buf[tid] = deg[tid];
        __syncthreads();
        #pragma unroll
        for (int ofs = 1; ofs < 512; ofs <<= 1) {
            int t = (tid >= ofs) ? buf[tid - ofs] : 0;
            __syncthreads();
            buf[tid] += t;
            __syncthreads();
        }
        int oe = buf[tid] - deg[tid];
        soff[tid] = oe;
        roff[nb + tid] = g * EPG + oe;
        if (tid == 511) roff[nb + 512] = g * EPG + buf[511];
        cnt[tid] = 1;
        csrc[g * EPG + oe] = nb + tid;
        __syncthreads();
        for (int i = tid; i < EPG_NL; i += 512) {
            int dl = ei[E + eb + i] - nb;
            int s  = ei[eb + i];
            int pos = atomicAdd(&cnt[dl], 1);
            csrc[g * EPG + soff[dl] + pos] = s;
        }
    } else if (b < NG + 768) {
        // ---- weight transpose+cast ----
        int idx = b - NG;
        int z, bx, by, Nc;
        if (idx < 512) { z = idx >> 8; int l = idx & 255; bx = l & 15; by = l >> 4; Nc = 512; }
        else { z = 2 + ((idx - 512) >> 7); int l = (idx - 512) & 127; bx = l & 7; by = l >> 3; Nc = 256; }
        const float* W = (z == 0) ? Wl1 : (z == 1) ? Wr1 : (z == 2) ? Wl2 : Wr2;
        unsigned short* th = (z == 0) ? wc1 : (z == 1) ? wc1 + 512 * 512
                           : (z == 2) ? wc2 : wc2 + 256 * 512;
        const int K = 512;
        float* t = (float*)sh;         // [32][33]
        int lx = tid & 31, ly = tid >> 5;   // ly in [0,16)
        #pragma unroll
        for (int r = ly; r < 32; r += 16)
            t[r * 33 + lx] = W[(size_t)(by * 32 + r) * Nc + bx * 32 + lx];
        __syncthreads();
        #pragma unroll
        for (int r = ly; r < 32; r += 16)
            th[(size_t)(bx * 32 + r) * K + by * 32 + lx] = f2bf_rn(t[lx * 33 + r]);
    } else if (b < NG + 771) {
        // ---- bias concat ----
        int i = (b - NG - 768) * 512 + tid;
        if (i < 512)        bcat1[i] = bl1[i];
        else if (i < 1024)  bcat1[i] = br1[i - 512];
        else if (i < 1280)  bcat2[i - 1024] = bl2[i - 1024];
        else if (i < 1536)  bcat2[i - 1024] = br2[i - 1280];
    } else {
        // ---- x cast (1024 blocks, grid-stride) ----
        int cb = b - NG - 771;
        for (int i = cb * 512 + tid; i < n4; i += 1024 * 512) {
            float4 v = ((const float4*)X)[i];
            ushort4 h;
            h.x = f2bf_rn(v.x); h.y = f2bf_rn(v.y);
            h.z = f2bf_rn(v.z); h.w = f2bf_rn(v.w);
            ((ushort4*)Xh)[i] = h;
        }
    }
}

// ---- 128x128 GEMM, 4 waves, pure bf16, 2-buffer dbuf (32KB -> 5 blk/CU) ----

__global__ __launch_bounds__(256) void gemm128b(
        const unsigned short* __restrict__ A,
        const unsigned short* __restrict__ B,
        const float* __restrict__ bias, unsigned short* __restrict__ C,
        int M, int K, int Nc) {
    constexpr int NQ  = 4;
    constexpr int BUF = 16384;
    __shared__ __align__(16) char smem[2 * BUF];

    int tid  = threadIdx.x;
    int wave = tid >> 6, lane = tid & 63;
    int wr = wave >> 1, wc = wave & 1;

    int bx = blockIdx.x, by = blockIdx.y;
    if ((gridDim.y & 7) == 0) {                 // XCD swizzle
        int d = blockIdx.y * gridDim.x + blockIdx.x;
        int x = d & 7, i = d >> 3;
        by = (i / gridDim.x) * 8 + x;
        bx = i % gridDim.x;
    }
    int m0 = by * 128, n0 = bx * 128;

    const unsigned short* gsrc[NQ];
    int loff[NQ];
    #pragma unroll
    for (int q = 0; q < NQ; ++q) {
        int o    = q * 4096 + tid * 16;
        int tile = o >> 13;
        int ot   = o & 8191;
        int row  = ot >> 6;
        int slot = (ot >> 4) & 3;
        int sl   = slot ^ ((row >> 1) & 3);
        const unsigned short* base =
            (tile == 0) ? (A + (size_t)(m0 + row) * K)
                        : (B + (size_t)(n0 + row) * K);
        gsrc[q] = base + sl * 8;
        loff[q] = q * 4096 + wave * 1024;
    }

    f32x4 acc[4][4];
    #pragma unroll
    for (int i = 0; i < 4; ++i)
        #pragma unroll
        for (int j = 0; j < 4; ++j) acc[i][j] = (f32x4){0.f, 0.f, 0.f, 0.f};

    int r = lane & 15, g = lane >> 4;
    int sw = (g ^ ((r >> 1) & 3)) * 16;

    #pragma unroll
    for (int q = 0; q < NQ; ++q) {
        __builtin_amdgcn_global_load_lds(
            (const __attribute__((address_space(1))) void*)(gsrc[q]),
            (__attribute__((address_space(3))) void*)(smem + loff[q]), 16, 0, 0);
        gsrc[q] += 32;
    }
    __syncthreads();

    const int NT = K >> 5;
    int cur = 0;
    for (int t = 0; t < NT; ++t) {
        if (t + 1 < NT) {
            #pragma unroll
            for (int q = 0; q < NQ; ++q) {
                __builtin_amdgcn_global_load_lds(
                    (const __attribute__((address_space(1))) void*)(gsrc[q]),
                    (__attribute__((address_space(3))) void*)(smem + loff[q] + (cur ^ BUF)),
                    16, 0, 0);
                gsrc[q] += 32;
            }
        }
        const char* sb = smem + cur;
        bf16x8 a[4], b[4];
        #pragma unroll
        for (int i = 0; i < 4; ++i) {
            int offA = (wr * 64 + i * 16 + r) * 64 + sw;
            int offB = (wc * 64 + i * 16 + r) * 64 + sw;
            a[i] = *(const bf16x8*)(sb + offA);
            b[i] = *(const bf16x8*)(sb + 8192 + offB);
        }
        __builtin_amdgcn_s_setprio(1);
        #pragma unroll
        for (int i = 0; i < 4; ++i)
            #pragma unroll
            for (int j = 0; j < 4; ++j)
                acc[i][j] = __builtin_amdgcn_mfma_f32_16x16x32_bf16(a[i], b[j], acc[i][j], 0, 0, 0);
        __builtin_amdgcn_s_setprio(0);
        __syncthreads();
        cur ^= BUF;
    }

    #pragma unroll
    for (int j = 0; j < 4; ++j) {
        int col = n0 + wc * 64 + j * 16 + r;
        float bv = bias[col];
        #pragma unroll
        for (int i = 0; i < 4; ++i) {
            int rowb = m0 + wr * 64 + i * 16 + g * 4;
            #pragma unroll
            for (int t = 0; t < 4; ++t)
                C[(size_t)(rowb + t) * Nc + col] = f2bf_rn(acc[i][j][t] + bv);
        }
    }
}

// -------- XCD swizzle for edge kernels: graph g -> XCD g%8 --------

__device__ __forceinline__ int edge_blk_swz(int blk, int swz) {
    if (swz) {
        int x = blk & 7, i = blk >> 3;
        blk = (i >> 7) * 1024 + x * 128 + (i & 127);
    }
    return blk;
}

// ---------------- Layer 1 edge kernel: wave per node, 8 ch/lane ----------------

__global__ __launch_bounds__(256) void gat_edge1(
        const unsigned short* __restrict__ xlr,
        const float* __restrict__ att, const float* __restrict__ bias,
        const int* __restrict__ roff, const int* __restrict__ csrc,
        unsigned short* __restrict__ Hh, int chunkN, int n0, int swz) {
    int blk = edge_blk_swz(blockIdx.x, swz);
    int node = blk * 4 + (threadIdx.x >> 6);
    if (node >= chunkN) return;
    int lane = threadIdx.x & 63;
    int bc = lane * 8;                 // head = lane/16
    float xrv[8], att6[8], att4[8];
    {
        uint4 t0 = *(const uint4*)&xlr[(size_t)node * 1024 + 512 + bc];
        const unsigned* u = (const unsigned*)&t0;
        #pragma unroll
        for (int j = 0; j < 4; ++j) {
            xrv[2*j]   = __uint_as_float(u[j] << 16);
            xrv[2*j+1] = __uint_as_float(u[j] & 0xFFFF0000u);
        }
        float4 a0 = *(const float4*)&att[bc];
        float4 a1 = *(const float4*)&att[bc + 4];
        float av[8] = {a0.x, a0.y, a0.z, a0.w, a1.x, a1.y, a1.z, a1.w};
        #pragma unroll
        for (int k = 0; k < 8; ++k) { att6[k] = 0.6f * av[k]; att4[k] = 0.4f * av[k]; }
    }
    float acc[8];
    float m = 0.0f, d = 0.0f;
    int e0 = roff[n0 + node], e1 = roff[n0 + node + 1];
    uint4 cv;
    {
        int s = csrc[e0] - n0;
        cv = *(const uint4*)&xlr[(size_t)s * 1024 + bc];
    }
    for (int e = e0; e < e1; ++e) {
        float xv[8];
        {
            const unsigned* u = (const unsigned*)&cv;
            #pragma unroll
            for (int j = 0; j < 4; ++j) {
                xv[2*j]   = __uint_as_float(u[j] << 16);
                xv[2*j+1] = __uint_as_float(u[j] & 0xFFFF0000u);
            }
        }
        if (e + 1 < e1) {              // prefetch next edge
            int s2 = csrc[e + 1] - n0;
            cv = *(const uint4*)&xlr[(size_t)s2 * 1024 + bc];
        }
        float p = 0.0f;
        #pragma unroll
        for (int k = 0; k < 8; ++k) {
            float t = xv[k] + xrv[k];
            p = fmaf(att6[k], t, p);
            p = fmaf(att4[k], fabsf(t), p);    // leaky = 0.6t + 0.4|t|
        }
        p += __shfl_xor(p, 1); p += __shfl_xor(p, 2);
        p += __shfl_xor(p, 4); p += __shfl_xor(p, 8);
        if (e == e0) {
            m = p; d = 1.0f;
            #pragma unroll
            for (int k = 0; k < 8; ++k) acc[k] = xv[k];
        } else if (p > m + 8.0f) {
            float sc = __expf(m - p);
            d = fmaf(d, sc, 1.0f);
            #pragma unroll
            for (int k = 0; k < 8; ++k) acc[k] = fmaf(acc[k], sc, xv[k]);
            m = p;
        } else {
            float w = __expf(p - m);
            d += w;
            #pragma unroll
            for (int k = 0; k < 8; ++k) acc[k] = fmaf(w, xv[k], acc[k]);
        }
    }
    float inv = 1.0f / d;
    ushort8 hv;
    #pragma unroll
    for (int k = 0; k < 8; ++k)
        ((unsigned short*)&hv)[k] = f2bf_rn(fmaf(acc[k], inv, bias[bc + k]));
    *(ushort8*)&Hh[(size_t)node * 512 + bc] = hv;
}

// ------- Layer 2 edge kernel: fused head-mean + feature-mean, 4 ch/lane -------

__global__ __launch_bounds__(256) void gat_edge2(
        const unsigned short* __restrict__ xlr,
        const float* __restrict__ att, const float* __restrict__ bias,
        const int* __restrict__ roff, const int* __restrict__ csrc,
        float* __restrict__ out, int chunkN, int n0, int swz) {
    int blk = edge_blk_swz(blockIdx.x, swz);
    int node = blk * 4 + (threadIdx.x >> 6);
    if (node >= chunkN) return;
    int lane = threadIdx.x & 63;
    int bc = lane * 4;                 // within [0,256); head = lane/16
    float xrv[4], att6[4], att4[4];
    {
        uint2 t0 = *(const uint2*)&xlr[(size_t)node * 512 + 256 + bc];
        const unsigned* u = (const unsigned*)&t0;
        #pragma unroll
        for (int j = 0; j < 2; ++j) {
            xrv[2*j]   = __uint_as_float(u[j] << 16);
            xrv[2*j+1] = __uint_as_float(u[j] & 0xFFFF0000u);
        }
        float4 a0 = *(const float4*)&att[bc];
        float av[4] = {a0.x, a0.y, a0.z, a0.w};
        #pragma unroll
        for (int k = 0; k < 4; ++k) { att6[k] = 0.6f * av[k]; att4[k] = 0.4f * av[k]; }
    }
    float acc[4];
    float m = 0.0f, d = 0.0f;
    int e0 = roff[n0 + node], e1 = roff[n0 + node + 1];
    uint2 cv;
    {
        int s = csrc[e0] - n0;
        cv = *(const uint2*)&xlr[(size_t)s * 512 + bc];
    }
    for (int e = e0; e < e1; ++e) {
        float xv[4];
        {
            const unsigned* u = (const unsigned*)&cv;
            #pragma unroll
            for (int j = 0; j < 2; ++j) {
                xv[2*j]   = __uint_as_float(u[j] << 16);
                xv[2*j+1] = __uint_as_float(u[j] & 0xFFFF0000u);
            }
        }
        if (e + 1 < e1) {
            int s2 = csrc[e + 1] - n0;
            cv = *(const uint2*)&xlr[(size_t)s2 * 512 + bc];
        }
        float p = 0.0f;
        #pragma unroll
        for (int k = 0; k < 4; ++k) {
            float t = xv[k] + xrv[k];
            p = fmaf(att6[k], t, p);
            p = fmaf(att4[k], fabsf(t), p);
        }
        p += __shfl_xor(p, 1); p += __shfl_xor(p, 2);
        p += __shfl_xor(p, 4); p += __shfl_xor(p, 8);
        if (e == e0) {
            m = p; d = 1.0f;
            #pragma unroll
            for (int k = 0; k < 4; ++k) acc[k] = xv[k];
        } else if (p > m + 8.0f) {
            float sc = __expf(m - p);
            d = fmaf(d, sc, 1.0f);
            #pragma unroll
            for (int k = 0; k < 4; ++k) acc[k] = fmaf(acc[k], sc, xv[k]);
            m = p;
        } else {
            float w = __expf(p - m);
            d += w;
            #pragma unroll
            for (int k = 0; k < 4; ++k) acc[k] = fmaf(w, xv[k], acc[k]);
        }
    }
    float inv = 1.0f / d;
    float v[4];
    #pragma unroll
    for (int k = 0; k < 4; ++k) v[k] = acc[k] * inv;
    #pragma unroll
    for (int k = 0; k < 4; ++k) {
        v[k] += __shfl_xor(v[k], 16);
        v[k] += __shfl_xor(v[k], 32);
    }
    int cb = (lane & 15) * 4;
    float s = 0.25f * (v[0] + v[1] + v[2] + v[3])
            + bias[cb] + bias[cb + 1] + bias[cb + 2] + bias[cb + 3];
    s += __shfl_xor(s, 1); s += __shfl_xor(s, 2);
    s += __shfl_xor(s, 4); s += __shfl_xor(s, 8);
    if (lane == 0) out[node] = s * (1.0f / 64.0f);
}

// ---------------- launch ----------------

extern "C" void kernel_launch(void* const* d_in, const int* in_sizes, int n_in,
                              void* d_out, int out_size, void* d_ws, size_t ws_size,
                              hipStream_t stream) {
    const float* x    = (const float*)d_in[0];
    const int*   ei   = (const int*)d_in[1];
    const float* Wl1  = (const float*)d_in[3];
    const float* bl1  = (const float*)d_in[4];
    const float* Wr1  = (const float*)d_in[5];
    const float* br1  = (const float*)d_in[6];
    const float* att1 = (const float*)d_in[7];
    const float* bias1= (const float*)d_in[8];
    const float* Wl2  = (const float*)d_in[9];
    const float* bl2  = (const float*)d_in[10];
    const float* Wr2  = (const float*)d_in[11];
    const float* br2  = (const float*)d_in[12];
    const float* att2 = (const float*)d_in[13];
    const float* bias2= (const float*)d_in[14];
    float* out = (float*)d_out;

    const int F = 512;
    const int N = in_sizes[0] / F;        // 32768
    const int E = in_sizes[1] / 2;        // 262144
    const int NG = 64;
    const int NPG = N / NG;               // 512
    const int EPG_NL = E / NG;            // 4096 non-loop edges per graph

    char* w = (char*)d_ws;
    int* roff = (int*)(w);                                   // N+1
    int* csrc = (int*)(w + 0x80000);                         // E+N
    unsigned short* wc1 = (unsigned short*)(w + 0x200000);   // [1024][512] bf16
    unsigned short* wc2 = (unsigned short*)(w + 0x400000);   // [512][512] bf16
    float* bcat1 = (float*)(w + 0x500000);
    float* bcat2 = (float*)(w + 0x501000);
    const size_t HDR = 6ull << 20;

    int chunkG = NG;
    while (chunkG > 1) {
        size_t need = HDR + 3ull * (size_t)chunkG * NPG * 512 * 4;
        if (need <= ws_size) break;
        chunkG >>= 1;
    }
    const int chunkN = chunkG * NPG;
    const size_t BSZ = (size_t)chunkN * 512 * 4;
    char* R1 = w + HDR;
    char* R2 = w + HDR + BSZ;
    const int swz = (chunkG % 8 == 0) ? 1 : 0;

    // Single fused prep dispatch. NOTE: the x-cast part covers the FULL x
    // (all 64 graphs) since chunkG=64 in practice; if chunked, the cast runs
    // once here and per-chunk GEMMs index into the full Xh buffer.
    unsigned short* XhFull = (unsigned short*)R1;   // bf16(x), chunk layout
    // If chunked (chunkG < NG), R1 only holds one chunk; fall back to
    // casting per chunk inside the loop. Detect via chunkG.
    const int full = (chunkG == NG) ? 1 : 0;
    prep_kernel<<<64 + 768 + 3 + 1024, 512, 0, stream>>>(
        ei, E, NPG, EPG_NL, roff, csrc,
        Wl1, Wr1, Wl2, Wr2, wc1, wc2,
        bl1, br1, bl2, br2, bcat1, bcat2,
        x, XhFull, full ? (N * 512 / 4) : 0, NG);

    for (int g0 = 0; g0 < NG; g0 += chunkG) {
        int n0 = g0 * NPG;
        unsigned short* Xh   = (unsigned short*)R1;
        unsigned short* xlr1 = (unsigned short*)R2;  // bf16 [chunkN][1024]
        unsigned short* Hh   = (unsigned short*)R1;  // reuse (Xh dead after L1 gemm)
        unsigned short* xlr2 = (unsigned short*)R2;  // bf16 [chunkN][512]

        if (!full) {
            // chunked fallback: cast this chunk's x via the prep kernel's
            // cast section only (blocks [NG+771, ...)); cheap re-dispatch.
            prep_kernel<<<64 + 768 + 3 + 1024, 512, 0, stream>>>(
                ei, E, NPG, EPG_NL, roff, csrc,
                Wl1, Wr1, Wl2, Wr2, wc1, wc2,
                bl1, br1, bl2, br2, bcat1, bcat2,
                x + (size_t)n0 * 512, Xh, chunkN * 512 / 4, NG);
        }
        gemm128b<<<dim3(1024/128, chunkN/128), 256, 0, stream>>>(
            Xh + (full ? (size_t)0 : 0), wc1, bcat1, xlr1, chunkN, 512, 1024);
        gat_edge1<<<(chunkN * 64) / 256, 256, 0, stream>>>(
            xlr1, att1, bias1, roff, csrc, Hh, chunkN, n0, swz);

        gemm128b<<<dim3(512/128, chunkN/128), 256, 0, stream>>>(
            Hh, wc2, bcat2, xlr2, chunkN, 512, 512);
        gat_edge2<<<(chunkN * 64) / 256, 256, 0, stream>>>(
            xlr2, att2, bias2, roff, csrc, out + n0, chunkN, n0, swz);
    }
}